// Round 1
// 253.098 us; speedup vs baseline: 1.0069x; 1.0069x over previous
//
#include <hip/hip_runtime.h>
#include <math.h>

// HOG layer: x (1,3,4096,4096) fp32 -> feat (511,511,36) fp32.
// Only pixels at (8i+7, 8j+7) are sampled. Per 16x16-cell block:
//   Phase A: coalesced float4 staging of the 51 needed image rows
//            (y = 8g+{6,7,8}) x 136 cols, channel-summed, into LDS.
//   Phase B: 17x17 compact cell histograms: (bin, vj, vj1) per cell
//            (only 2 of 9 bins are ever nonzero).
//   Phase C: 4 lanes per output cell (one quadrant each), shfl reduce
//            for the L2 norm, then a per-wave in-LDS transpose (reusing
//            the dead raw[] buffer) so global stores are fully
//            coalesced: 2x dwordx4 + 1x dword per lane instead of
//            9 scalar dword stores at 36B lane stride.

#define IMG 4096
#define CSTRIDE (4096 * 4096)
#define NOUT 511
#define HT 17          // cells per block dim (16+1)
#define NROWS 51       // 3*HT image rows staged
#define NQ 34          // float4 quads per staged row
#define RS 136         // floats per staged row (NQ*4)

__global__ __launch_bounds__(256) void hog_kernel(const float* __restrict__ x,
                                                  float* __restrict__ out) {
    __shared__ float raw[NROWS * RS];      // 27744 B; reused as store-stage in C
    __shared__ float4 hist[HT * HT];       // (i0, vj, vj1, -) 4624 B

    const int bi = blockIdx.y, bj = blockIdx.x, tid = threadIdx.x;
    const int col0 = 128 * bj + 4;         // 16B-aligned staging base column

    // ---- Phase A: coalesced load + channel sum -> LDS -------------------
    // row rr = 3r+dt  <->  image row y = 8*(16bi+r) + 6 + dt
    for (int t = tid; t < NROWS * NQ; t += 256) {
        const int rr = t / NQ;
        const int q  = t - rr * NQ;
        const int r  = rr / 3;
        const int dt = rr - 3 * r;
        const int y  = 128 * bi + 8 * r + 6 + dt;
        const int gc = col0 + 4 * q;
        float4 v = make_float4(0.f, 0.f, 0.f, 0.f);
        if (y < IMG && gc + 3 < IMG) {           // OOB -> zeros == jnp.pad
            const size_t base = (size_t)y * IMG + gc;
            const float4 a = *(const float4*)(x + base);
            const float4 b = *(const float4*)(x + base + (size_t)CSTRIDE);
            const float4 c = *(const float4*)(x + base + 2 * (size_t)CSTRIDE);
            v.x = (a.x + b.x) + c.x;
            v.y = (a.y + b.y) + c.y;
            v.z = (a.z + b.z) + c.z;
            v.w = (a.w + b.w) + c.w;
        }
        *(float4*)&raw[rr * RS + 4 * q] = v;     // 16B-aligned ds_write_b128
    }
    __syncthreads();

    // ---- Phase B: 17x17 compact cell histograms ------------------------
    // cell (r,k): sample pixel (8*(16bi+r)+7, 8*(16bj+k)+7)
    for (int cell = tid; cell < HT * HT; cell += 256) {
        const int r = cell / HT;
        const int k = cell - r * HT;
        const float s_up = raw[(3 * r    ) * RS + 8 * k + 3];
        const float s_lf = raw[(3 * r + 1) * RS + 8 * k + 2];
        const float s_rt = raw[(3 * r + 1) * RS + 8 * k + 4];
        const float s_dn = raw[(3 * r + 2) * RS + 8 * k + 3];

        const float g_v = s_dn - s_up;
        const float g_h = s_rt - s_lf;
        const float mag = sqrtf(g_v * g_v + g_h * g_h + 1e-6f);
        const float ang = fabsf(atanf(g_h / (g_v + 1e-9f)) * 57.29577951308232f);
        const float jf  = floorf(ang * 0.05f - 0.5f);       // in {-1..4}
        const float vj  = mag * ((20.0f * (jf + 1.5f) - ang) * 0.05f);
        const float vj1 = mag - vj;
        float i0f = jf; if (i0f < 0.f) i0f += 9.f;          // mod 9, range-based
        hist[cell] = make_float4(i0f, vj, vj1, 0.f);
    }
    __syncthreads();   // raw[] is dead past here; reused as scratch below

    // ---- Phase C: normalize + per-wave transpose + coalesced stores ----
    const int l  = tid & 63;         // lane
    const int w  = tid >> 6;         // wave 0..3
    const int p  = l & 3;            // quadrant: h00,h01,h10,h11
    const int cq = l >> 2;           // tx: 0..15, cell within wave's row
    float* scratch = &raw[w * 576];  // wave-private 2304 B stage

    const int oj0 = 16 * bj;
    const bool colfull = (bj < 31);  // all 16 cells in-bounds column-wise
    for (int it = 0; it < 4; ++it) {
        const int ty = it * 4 + w;   // each wave owns one output row per it
        const int hr = ty + (p >> 1);
        const int hc = cq + (p & 1);
        const float4 h = hist[hr * HT + hc];
        const int i0 = (int)h.x;
        const int i1 = (i0 == 8) ? 0 : i0 + 1;
        float ss = h.y * h.y + h.z * h.z;       // only 2 bins are nonzero
        ss += __shfl_xor(ss, 1);                // reduce across 4 quadrant lanes
        ss += __shfl_xor(ss, 2);
        const float inv = 1.0f / (sqrtf(ss) + 1e-9f);
        const float va = h.y * inv;
        const float vb = h.z * inv;

        // expand the 2 nonzero bins into the 9-float quadrant, into LDS
        float* sp = &scratch[cq * 36 + p * 9];  // 2-way banks (free)
#pragma unroll
        for (int b = 0; b < 9; ++b)
            sp[b] = (b == i0) ? va : ((b == i1) ? vb : 0.0f);

        // wave-internal visibility of all 64 lanes' ds_writes
        asm volatile("s_waitcnt lgkmcnt(0)" ::: "memory");

        const int oi = 16 * bi + ty;
        if (oi < NOUT) {
            float* obase = out + ((size_t)oi * NOUT + oj0) * 36;  // 144B-aligned
            if (colfull) {
                // 576 contiguous dwords: 2x dwordx4 + 1x dword per lane
                const float4 v0 = *(const float4*)&scratch[4 * l];
                const float4 v1 = *(const float4*)&scratch[256 + 4 * l];
                const float  v2 = scratch[512 + l];
                *(float4*)(obase + 4 * l)       = v0;
                *(float4*)(obase + 256 + 4 * l) = v1;
                obase[512 + l]                  = v2;
            } else {
                // bj==31: only cells tx<15 valid -> dwords 0..539, coalesced
#pragma unroll
                for (int s = 0; s < 9; ++s) {
                    const int d = s * 64 + l;
                    if (d < 540) obase[d] = scratch[d];
                }
            }
        }
    }
}

extern "C" void kernel_launch(void* const* d_in, const int* in_sizes, int n_in,
                              void* d_out, int out_size, void* d_ws, size_t ws_size,
                              hipStream_t stream) {
    (void)in_sizes; (void)n_in; (void)d_ws; (void)ws_size; (void)out_size;
    const float* x = (const float*)d_in[0];
    float* out = (float*)d_out;
    dim3 grid(32, 32);   // 16x16 output cells per block, 511x511 total
    dim3 block(256);
    hipLaunchKernelGGL(hog_kernel, grid, block, 0, stream, x, out);
}